// Round 1
// 324.769 us; speedup vs baseline: 1.1216x; 1.1216x over previous
//
#include <hip/hip_runtime.h>
#include <math.h>

// OFPenalty: power-iteration eigen-penalty on AAT = W W^T per batch, never
// materializing AAT. Round 3: async-pipelined k_step.
//  - Each block = (split s in 0..7, batch b). It owns ALL 512 c-rows and the
//    d-chunks {s, s+8, ...} of 49 chunks of 16 columns (784 = 49*16).
//  - Chunk loop is double-buffered via global_load_lds (16B) with counted
//    s_waitcnt vmcnt(8) + raw s_barrier, so next chunk's HBM loads are in
//    flight across the whole compute phase (u reduce + v accumulate).
//  - v accumulates in registers across chunks -> ONE plain store per c into a
//    per-split partial buffer [b][8][512]. No atomics, no zero-fill kernel.
//  - Downstream consumers (k_step phase A, k_mid, k_fin2) sum the 8 partials.
// A: (64, 512, 28, 28) fp32 -> W: (64, 512, 784). x0: (64, 512, 1).

#define BB 64
#define CC 512
#define DD 784
#define DCH 16
#define NCH 49          // 49 chunks of 16, no tail
#define NSPLIT 8
#define F4PR 196        // float4 per row = DD/4
#define FEPS 1e-12f

__device__ __forceinline__ void gload16(const float4* gp, float4* lp) {
    __builtin_amdgcn_global_load_lds(
        (const __attribute__((address_space(1))) void*)gp,
        (__attribute__((address_space(3))) void*)lp, 16, 0, 0);
}

__device__ __forceinline__ float blk_reduce(float s, float* red) {
    for (int off = 32; off; off >>= 1) s += __shfl_down(s, off, 64);
    int w = threadIdx.x >> 6;
    if ((threadIdx.x & 63) == 0) red[w] = s;
    __syncthreads();
    float t = red[0] + red[1] + red[2] + red[3];
    __syncthreads();                       // allow red[] reuse by caller
    return t;
}

// vout[b][s][c] = partial of (AAT_b * normalize(sum_p xin[b][p][:]))_c over
// this split's d-chunks. xin has nparts partial segments per b (1 or 8).
__global__ __launch_bounds__(256, 2)
void k_step(const float* __restrict__ A, const float* __restrict__ xin,
            const int nparts, float* __restrict__ vout) {
    __shared__ float xs[CC];
    __shared__ float tile[2][CC * DCH];    // 2 x 32 KB
    __shared__ float uw[4][DCH];
    __shared__ float usd[DCH];
    __shared__ float red[4];

    const int tid = threadIdx.x;
    const int b = blockIdx.y;
    const int s = blockIdx.x;
    const int lane = tid & 63;
    const int w = tid >> 6;
    const int rr = tid >> 2, widx = tid & 3;   // row-group / float4-in-chunk

    const float4* Ap = (const float4*)(A + (size_t)b * CC * DD);

    // ---- prologue: issue chunk s into buffer 0 (async, overlaps phase A)
    {
        float4* lbase = &((float4*)tile[0])[w * 64];
        const float4* gbase = Ap + (size_t)rr * F4PR + s * 4 + widx;
#pragma unroll
        for (int i = 0; i < 8; i++)
            gload16(gbase + (size_t)i * 64 * F4PR, lbase + i * 256);
    }

    // ---- phase A: normalize input (sum nparts partial segments), once/block
    const float* xp = xin + (size_t)b * nparts * CC;
    float xv0 = 0.f, xv1 = 0.f;
    for (int p = 0; p < nparts; p++) {
        xv0 += xp[p * CC + tid];
        xv1 += xp[p * CC + tid + 256];
    }
    float ss = blk_reduce(xv0 * xv0 + xv1 * xv1, red);
    float rn = 1.0f / fmaxf(sqrtf(ss), FEPS);
    xs[tid] = xv0 * rn;
    xs[tid + 256] = xv1 * rn;
    // xs visibility across waves is covered by bar1 (lgkmcnt(0)+s_barrier).

    float v0 = 0.f, v1 = 0.f;
    int buf = 0;
    const int c0 = tid, c1 = tid + 256;
    const int lh = lane >> 1;

    for (int ch = s; ch < NCH; ch += NSPLIT) {
        // issue next chunk into the other buffer, then wait for CURRENT tile
        const int nxt = ch + NSPLIT;
        if (nxt < NCH) {
            float4* lbase = &((float4*)tile[buf ^ 1])[w * 64];
            const float4* gbase = Ap + (size_t)rr * F4PR + nxt * 4 + widx;
#pragma unroll
            for (int i = 0; i < 8; i++)
                gload16(gbase + (size_t)i * 64 * F4PR, lbase + i * 256);
            __builtin_amdgcn_sched_barrier(0);
            asm volatile("s_waitcnt vmcnt(8)" ::: "memory");   // keep 8 in flight
        } else {
            __builtin_amdgcn_sched_barrier(0);
            asm volatile("s_waitcnt vmcnt(0)" ::: "memory");
        }
        asm volatile("s_waitcnt lgkmcnt(0)" ::: "memory");
        __builtin_amdgcn_s_barrier();                          // bar1: tile[buf] ready
        __builtin_amdgcn_sched_barrier(0);

        // ---- u-phase: u_d = <A[:, d0+d], x_hat>, d = widx*4+j
        float4 ua = make_float4(0.f, 0.f, 0.f, 0.f);
        const float4* t4p = (const float4*)tile[buf];
#pragma unroll
        for (int i = 0; i < 8; i++) {
            float4 a4 = t4p[tid + i * 256];
            float x = xs[rr + i * 64];
            ua.x += a4.x * x; ua.y += a4.y * x;
            ua.z += a4.z * x; ua.w += a4.w * x;
        }
        // reduce across lanes sharing widx (bits 2..5 of lane)
#pragma unroll
        for (int off = 4; off <= 32; off <<= 1) {
            ua.x += __shfl_xor(ua.x, off, 64);
            ua.y += __shfl_xor(ua.y, off, 64);
            ua.z += __shfl_xor(ua.z, off, 64);
            ua.w += __shfl_xor(ua.w, off, 64);
        }
        if (lane < 4) {
            uw[w][lane * 4 + 0] = ua.x; uw[w][lane * 4 + 1] = ua.y;
            uw[w][lane * 4 + 2] = ua.z; uw[w][lane * 4 + 3] = ua.w;
        }
        __builtin_amdgcn_sched_barrier(0);
        asm volatile("s_waitcnt lgkmcnt(0)" ::: "memory");
        __builtin_amdgcn_s_barrier();                          // bar2: uw written
        __builtin_amdgcn_sched_barrier(0);

        if (tid < DCH)
            usd[tid] = uw[0][tid] + uw[1][tid] + uw[2][tid] + uw[3][tid];
        __builtin_amdgcn_sched_barrier(0);
        asm volatile("s_waitcnt lgkmcnt(0)" ::: "memory");
        __builtin_amdgcn_s_barrier();                          // bar3: usd ready
        __builtin_amdgcn_sched_barrier(0);

        // ---- v-phase: v_c += sum_d tile[c][d] * u_d  (registers, cross-chunk)
        // d staggered by lane/2 -> 2-way bank alias (free), usd broadcast.
        const float* tp = tile[buf];
#pragma unroll
        for (int k = 0; k < DCH; k++) {
            int d = (k + lh) & (DCH - 1);
            float ud = usd[d];
            v0 += tp[c0 * DCH + d] * ud;
            v1 += tp[c1 * DCH + d] * ud;
        }
        __builtin_amdgcn_sched_barrier(0);
        asm volatile("s_waitcnt lgkmcnt(0)" ::: "memory");
        __builtin_amdgcn_s_barrier();   // bar4: all waves done with tile[buf]
        __builtin_amdgcn_sched_barrier(0);
        buf ^= 1;
    }

    float* vp = vout + ((size_t)b * NSPLIT + s) * CC;
    vp[c0] = v0;
    vp[c1] = v1;
}

// largest_b = <t5, x1>/<x1,x1>, x1 = t4/||t4||;  y = t5 - largest*x1
// t4, t5 are 8-way partial buffers [b][8][512].
__global__ void k_mid(const float* __restrict__ t4, const float* __restrict__ t5,
                      float* __restrict__ acc, float* __restrict__ y) {
    __shared__ float red[4];
    int b = blockIdx.x;
    const float* p4 = t4 + (size_t)b * NSPLIT * CC;
    const float* p5 = t5 + (size_t)b * NSPLIT * CC;
    float a0 = 0.f, a1 = 0.f, b0 = 0.f, b1 = 0.f;
    for (int p = 0; p < NSPLIT; p++) {
        a0 += p4[p * CC + threadIdx.x]; a1 += p4[p * CC + threadIdx.x + 256];
        b0 += p5[p * CC + threadIdx.x]; b1 += p5[p * CC + threadIdx.x + 256];
    }
    float ss4 = blk_reduce(a0 * a0 + a1 * a1, red);
    float rn = 1.0f / fmaxf(sqrtf(ss4), FEPS);
    float x10 = a0 * rn, x11 = a1 * rn;
    float num = blk_reduce(b0 * x10 + b1 * x11, red);
    float den = blk_reduce(x10 * x10 + x11 * x11, red);
    float largest = num / den;
    float* yp = y + (size_t)b * CC;
    yp[threadIdx.x] = b0 - largest * x10;
    yp[threadIdx.x + 256] = b1 - largest * x11;
    if (threadIdx.x == 0) acc[b * 8 + 0] = largest;
}

// dotwx = <w, x2>, den2 = <x2,x2>, x2 = y/||y||. w is partial [b][8][512].
__global__ void k_fin2(const float* __restrict__ w, const float* __restrict__ y,
                       float* __restrict__ acc) {
    __shared__ float red[4];
    int b = blockIdx.x;
    const float* wp = w + (size_t)b * NSPLIT * CC;
    const float* yp = y + (size_t)b * CC;
    float w0 = 0.f, w1 = 0.f;
    for (int p = 0; p < NSPLIT; p++) {
        w0 += wp[p * CC + threadIdx.x];
        w1 += wp[p * CC + threadIdx.x + 256];
    }
    float y0 = yp[threadIdx.x], y1 = yp[threadIdx.x + 256];
    float ssy = blk_reduce(y0 * y0 + y1 * y1, red);
    float rn = 1.0f / fmaxf(sqrtf(ssy), FEPS);
    float x20 = y0 * rn, x21 = y1 * rn;
    float dotwx = blk_reduce(w0 * x20 + w1 * x21, red);
    float den2 = blk_reduce(x20 * x20 + x21 * x21, red);
    if (threadIdx.x == 0) { acc[b * 8 + 1] = dotwx; acc[b * 8 + 2] = den2; }
}

__global__ void k_out(const float* __restrict__ acc, float* __restrict__ out) {
    int b = threadIdx.x;                   // 64 threads = 1 wave
    float largest = acc[b * 8 + 0];
    float dotwx   = acc[b * 8 + 1];
    float den2    = acc[b * 8 + 2];
    float tmp = (dotwx - largest * den2) / den2;
    float smallest = tmp + largest;
    float r = largest / smallest - 1.0f;
    float pen = r * r;                     // BETA = 1
    for (int off = 32; off; off >>= 1) pen += __shfl_down(pen, off, 64);
    if (b == 0) out[0] = pen / (float)BB;
}

extern "C" void kernel_launch(void* const* d_in, const int* in_sizes, int n_in,
                              void* d_out, int out_size, void* d_ws, size_t ws_size,
                              hipStream_t stream) {
    const float* A  = (const float*)d_in[0];
    const float* x0 = (const float*)d_in[1];
    float* out = (float*)d_out;
    float* ws = (float*)d_ws;

    float* acc = ws;                        // 512 floats (64 x 8)
    float* y   = ws + 512;                  // BB*CC floats (dense)
    float* PA  = y + BB * CC;               // BB*NSPLIT*CC floats (partial)
    float* PB  = PA + BB * NSPLIT * CC;     // BB*NSPLIT*CC floats (partial)

    dim3 gS(NSPLIT, BB);
    k_step<<<gS, 256, 0, stream>>>(A, x0, 1, PA);        // t1
    k_step<<<gS, 256, 0, stream>>>(A, PA, NSPLIT, PB);   // t2
    k_step<<<gS, 256, 0, stream>>>(A, PB, NSPLIT, PA);   // t3
    k_step<<<gS, 256, 0, stream>>>(A, PA, NSPLIT, PB);   // t4 (x1 = t4^)
    k_step<<<gS, 256, 0, stream>>>(A, PB, NSPLIT, PA);   // t5 = AAT x1

    k_mid<<<BB, 256, 0, stream>>>(PB, PA, acc, y);       // largest, y

    k_step<<<gS, 256, 0, stream>>>(A, y, 1, PB);         // w = AAT x2

    k_fin2<<<BB, 256, 0, stream>>>(PB, y, acc);
    k_out<<<1, 64, 0, stream>>>(acc, out);
}